// Round 5
// baseline (306.228 us; speedup 1.0000x reference)
//
#include <hip/hip_runtime.h>

namespace {
constexpr int kL    = 2048;
constexpr int kV    = 25;
constexpr int kTL   = 8;
constexpr int kXsC  = kL * kV;          // 51200
constexpr long kXsN = 64L * kXsC;

typedef __attribute__((ext_vector_type(8))) short  bf16x8;
typedef __attribute__((ext_vector_type(4))) float  f32x4;
typedef __attribute__((ext_vector_type(4))) unsigned short us4;

__device__ __forceinline__ unsigned short f2b(float f) {
  union { float f; unsigned u; } x; x.f = f;
  unsigned r = x.u + 0x7FFF + ((x.u >> 16) & 1);
  return (unsigned short)(r >> 16);
}
}

// ws layout (ushort):
//  [0, 12288)      stage-2 A-frags bf16[4 mt][6 ksg][64 lane][8]   (W[c][k=p*64+ci])
//  [12288, 15360)  stage-1 B-frags bf16[3 p][2 wt][64 lane][8]     (A[p][v][w], 0-pad)
//  byte 30720      bias2 fp32[64][25]
__global__ void stgcn_pre(const float* __restrict__ A,
                          const float* __restrict__ cw,
                          const float* __restrict__ cb,
                          unsigned short* __restrict__ wsu) {
  int t = threadIdx.x;
  for (int i = t; i < 4 * 6 * 64 * 8; i += 256) {
    int j = i & 7, lane = (i >> 3) & 63;
    int rem = i >> 9;              // 0..23
    int ksg = rem % 6, mt = rem / 6;
    int c = 16 * mt + (lane & 15);
    int k = 32 * ksg + (lane >> 4) * 8 + j;
    int p = k >> 6, ci = k & 63;
    wsu[i] = f2b(cw[(p * 64 + c) * 64 + ci]);
  }
  for (int i = t; i < 3 * 2 * 64 * 8; i += 256) {
    int j = i & 7, lane = (i >> 3) & 63, wt = (i >> 9) & 1, p = i >> 10;
    int w = 16 * wt + (lane & 15);
    int v = (lane >> 4) * 8 + j;
    float val = (v < kV && w < kV) ? A[(p * kV + v) * kV + w] : 0.f;
    wsu[12288 + i] = f2b(val);
  }
  float* bias2 = (float*)((char*)wsu + 30720);
  for (int i = t; i < 64 * kV; i += 256) {
    int c = i / kV, w = i % kV;
    float s = 0.f;
    for (int p = 0; p < 3; ++p) {
      float as = 0.f;
      for (int v = 0; v < kV; ++v) as += A[(p * kV + v) * kV + w];
      s += cb[p * 64 + c] * as;
    }
    bias2[i] = s;
  }
}

__global__ __launch_bounds__(512, 6)
void stgcn_main(const float* __restrict__ x,
                const unsigned short* __restrict__ wsu,
                float* __restrict__ out) {
  // Unioned LDS, 40960 B -> 3 blocks/CU:
  //  phase A/B: SX bf16 [m=ci*8+dl][40] (8-col blocks XOR-swizzled by ci&3) -- R3 layout
  //  p-loop:    sYs bf16 [nidx 208][72]                                     -- R3 layout
  __shared__ unsigned short sBuf[512 * 40];

  const int t   = threadIdx.x;
  const int lam = t & 63;
  const int wid = t >> 6;               // 0..7
  const int h   = lam >> 4;
  const int r16 = lam & 15;
  const int l0  = blockIdx.x * kTL;
  const float* xn = x + (long)blockIdx.y * kXsN;
  float* outn     = out + (long)blockIdx.y * kXsN;
  const float* bias2 = (const float*)((const char*)wsu + 30720);

  // ---- Phase A: rolling window sums, global -> regs -> LDS (bf16, m=ci*8+dl) ----
  {
    const int ci = t >> 3, q = t & 7;
    const int rowb = ci * 8 * 40;
    if (q == 7) {
      const int c4 = ((3 ^ (ci & 3)) << 3) | 4;   // logical col 28
      us4 z = {0, 0, 0, 0};
      #pragma unroll
      for (int dl = 0; dl < 8; ++dl) *(us4*)&sBuf[rowb + dl * 40 + c4] = z;
    } else {
      const int colL = 4 * q;
      const int c4 = (((colL >> 3) ^ (ci & 3)) << 3) | (colL & 7);
      const float* xr = xn + (long)ci * kXsC + (long)(l0 - 8) * kV + colL;
      const bool full = (q < 6);                  // q==6 -> only v=24 valid
      float a0 = 0.f, a1 = 0.f, a2 = 0.f, a3 = 0.f;
      if (l0) {
        #pragma unroll
        for (int j = 0; j < 9; ++j) {
          const float* r = xr + j * kV;
          a0 += r[0];
          if (full) { a1 += r[1]; a2 += r[2]; a3 += r[3]; }
        }
      } else {
        const float* r = xr + 8 * kV;
        a0 = r[0];
        if (full) { a1 = r[1]; a2 = r[2]; a3 = r[3]; }
      }
      #pragma unroll
      for (int dl = 0; dl < 8; ++dl) {
        us4 o = { f2b(a0), f2b(a1), f2b(a2), f2b(a3) };
        *(us4*)&sBuf[rowb + dl * 40 + c4] = o;
        if (dl < 7) {
          const float* pn = xr + (dl + 9) * kV;
          a0 += pn[0];
          if (full) { a1 += pn[1]; a2 += pn[2]; a3 += pn[3]; }
          if (l0) {
            const float* po = xr + dl * kV;
            a0 -= po[0];
            if (full) { a1 -= po[1]; a2 -= po[2]; a3 -= po[3]; }
          }
        }
      }
    }
  }
  __syncthreads();

  // ---- Phase B: hoist this lane's 4 A-fragments into registers (p-invariant) ----
  bf16x8 af[4];
  #pragma unroll
  for (int i = 0; i < 4; ++i) {
    const int mt = wid * 4 + i;
    const int m  = 16 * mt + r16;
    const int cia = m >> 3;
    af[i] = *(const bf16x8*)&sBuf[m * 40 + ((h ^ (cia & 3)) << 3)];
  }
  __syncthreads();   // SX fully consumed; sBuf becomes sYs[208][72]

  // zero sYs pad rows 200..207
  for (int i = t; i < 8 * 72; i += 512) sBuf[200 * 72 + i] = 0;

  f32x4 acc[7];
  #pragma unroll
  for (int nt = 0; nt < 7; ++nt) acc[nt] = (f32x4){0.f, 0.f, 0.f, 0.f};

  const int nh  = wid >> 2;       // stage2: n-half
  const int mt2 = wid & 3;        // stage2: c-tile
  const int ntb = nh ? 7 : 0;

  for (int p = 0; p < 3; ++p) {
    // ---- stage 1: Y[nidx=(dl*25+w)][ci] = sum_v SX[(ci,dl)][v] * A[p][v][w] ----
    #pragma unroll
    for (int wt = 0; wt < 2; ++wt) {
      bf16x8 bf = *(const bf16x8*)&wsu[12288 + ((p * 2 + wt) * 64 + lam) * 8];
      const int w = 16 * wt + r16;
      const bool wok = (w < kV);
      #pragma unroll
      for (int i = 0; i < 4; ++i) {
        const int mt = wid * 4 + i;
        f32x4 c0 = {0.f, 0.f, 0.f, 0.f};
        c0 = __builtin_amdgcn_mfma_f32_16x16x32_bf16(af[i], bf, c0, 0, 0, 0);
        if (wok) {
          const int mb = 16 * mt + 4 * h;
          const int cw_ = mb >> 3, dl0 = mb & 7;
          #pragma unroll
          for (int r = 0; r < 4; ++r)
            sBuf[((dl0 + r) * kV + w) * 72 + cw_] = f2b(c0[r]);
        }
      }
    }
    __syncthreads();

    // ---- stage 2: es[c][nidx] += sum_ci W[c][p*64+ci] * Y[nidx][ci] ----
    #pragma unroll
    for (int ksl = 0; ksl < 2; ++ksl) {
      bf16x8 wf = *(const bf16x8*)&wsu[((mt2 * 6 + p * 2 + ksl) * 64 + lam) * 8];
      #pragma unroll
      for (int nt = 0; nt < 7; ++nt) {
        if (nh == 0 || nt < 6) {
          bf16x8 yf = *(const bf16x8*)&sBuf[(16 * (ntb + nt) + r16) * 72 + 32 * ksl + 8 * h];
          acc[nt] = __builtin_amdgcn_mfma_f32_16x16x32_bf16(wf, yf, acc[nt], 0, 0, 0);
        }
      }
    }
    if (p < 2) __syncthreads();
  }

  // ---- Epilogue: + cnt*bias2 + residual (global, cache-hot), ReLU, store ----
  const int cb4 = 16 * mt2 + 4 * h;
  #pragma unroll
  for (int nt = 0; nt < 7; ++nt) {
    if (nh == 0 || nt < 6) {
      int nidx = 16 * (ntb + nt) + r16;
      if (nidx < 200) {
        int dl = nidx / 25, wv = nidx - 25 * dl;
        float cnt = l0 ? 9.f : (float)(dl + 1);
        long base = (long)(l0 + dl) * kV + wv;
        #pragma unroll
        for (int r = 0; r < 4; ++r) {
          int c = cb4 + r;
          float val = acc[nt][r] + cnt * bias2[c * kV + wv] + xn[(long)c * kXsC + base];
          outn[(long)c * kXsC + base] = fmaxf(val, 0.f);
        }
      }
    }
  }
}

extern "C" void kernel_launch(void* const* d_in, const int* in_sizes, int n_in,
                              void* d_out, int out_size, void* d_ws, size_t ws_size,
                              hipStream_t stream) {
  const float* x  = (const float*)d_in[0];
  const float* A  = (const float*)d_in[1];
  const float* cw = (const float*)d_in[2];
  const float* cb = (const float*)d_in[3];
  unsigned short* wsu = (unsigned short*)d_ws;   // needs 37120 B

  hipLaunchKernelGGL(stgcn_pre, dim3(1), dim3(256), 0, stream, A, cw, cb, wsu);
  hipLaunchKernelGGL(stgcn_main, dim3(kL / kTL, 16), dim3(512), 0, stream,
                     x, wsu, (float*)d_out);
}